// Round 1
// baseline (2144.286 us; speedup 1.0000x reference)
//
#include <hip/hip_runtime.h>
#include <cstdint>

#define B_ROWS 65536
#define DIM_IN 784
#define DIM1   512
#define DIM2   256
#define DIMZ   10
#define VOCAB  64

#define BM 128
#define BN 128
#define BK 16

// ---------------------------------------------------------------------------
// Generic fp32 GEMM: C[M,N] = act(A[M,K] @ W[K,N] + bias[N])
// EPI: 1 = relu, 2 = sigmoid
// 256 threads, 128x128 block tile, 8x8 per-thread micro-tile (split 4+4 at
// stride 64 so LDS reads are 256B-contiguous per 16 lanes -> conflict-free).
// ---------------------------------------------------------------------------
template<int EPI>
__global__ __launch_bounds__(256)
void gemm_bias_act(const float* __restrict__ A, const float* __restrict__ W,
                   const float* __restrict__ bias, float* __restrict__ C,
                   int N, int K) {
  __shared__ __align__(16) float As[BK][BM + 4];   // A^T tile: As[k][m]
  __shared__ __align__(16) float Bs[BK][BN + 4];   // B tile:   Bs[k][n]

  const int tid  = threadIdx.x;
  const int row0 = blockIdx.y * BM;
  const int col0 = blockIdx.x * BN;
  const int ty   = tid >> 4;    // 0..15
  const int tx   = tid & 15;    // 0..15

  float acc[8][8];
#pragma unroll
  for (int i = 0; i < 8; i++)
#pragma unroll
    for (int j = 0; j < 8; j++) acc[i][j] = 0.f;

  for (int kt = 0; kt < K; kt += BK) {
    // ---- stage A tile (transposed into LDS) ----
#pragma unroll
    for (int i = 0; i < 2; i++) {
      int q  = tid + i * 256;       // 0..511
      int r  = q >> 2;              // 0..127 (tile row)
      int kq = q & 3;               // which float4 of the 16-wide k slice
      const float4 v = *reinterpret_cast<const float4*>(
          A + (size_t)(row0 + r) * K + kt + kq * 4);
      As[kq * 4 + 0][r] = v.x;
      As[kq * 4 + 1][r] = v.y;
      As[kq * 4 + 2][r] = v.z;
      As[kq * 4 + 3][r] = v.w;
    }
    // ---- stage B tile ----
#pragma unroll
    for (int i = 0; i < 2; i++) {
      int q  = tid + i * 256;       // 0..511
      int kr = q >> 5;              // 0..15
      int cq = q & 31;              // 0..31  (float4 column)
      int c  = col0 + cq * 4;
      float4 v = make_float4(0.f, 0.f, 0.f, 0.f);
      if (c < N)
        v = *reinterpret_cast<const float4*>(W + (size_t)(kt + kr) * N + c);
      *reinterpret_cast<float4*>(&Bs[kr][cq * 4]) = v;
    }
    __syncthreads();

#pragma unroll
    for (int kk = 0; kk < BK; kk++) {
      float a[8], b[8];
      *reinterpret_cast<float4*>(a)     = *reinterpret_cast<const float4*>(&As[kk][ty * 4]);
      *reinterpret_cast<float4*>(a + 4) = *reinterpret_cast<const float4*>(&As[kk][64 + ty * 4]);
      *reinterpret_cast<float4*>(b)     = *reinterpret_cast<const float4*>(&Bs[kk][tx * 4]);
      *reinterpret_cast<float4*>(b + 4) = *reinterpret_cast<const float4*>(&Bs[kk][64 + tx * 4]);
#pragma unroll
      for (int i = 0; i < 8; i++)
#pragma unroll
        for (int j = 0; j < 8; j++)
          acc[i][j] = fmaf(a[i], b[j], acc[i][j]);
    }
    __syncthreads();
  }

  // ---- epilogue: bias + activation + store ----
#pragma unroll
  for (int i = 0; i < 8; i++) {
    int r = row0 + ((i < 4) ? (ty * 4 + i) : (64 + ty * 4 + i - 4));
#pragma unroll
    for (int jh = 0; jh < 2; jh++) {
      int c = col0 + jh * 64 + tx * 4;
      if (c < N) {
        float s[4];
#pragma unroll
        for (int j = 0; j < 4; j++) {
          float v = acc[i][jh * 4 + j] + bias[c + j];
          if (EPI == 1) v = fmaxf(v, 0.f);
          if (EPI == 2) v = 1.f / (1.f + expf(-v));
          s[j] = v;
        }
        float4 o = make_float4(s[0], s[1], s[2], s[3]);
        *reinterpret_cast<float4*>(C + (size_t)r * N + c) = o;
      }
    }
  }
}

// ---------------------------------------------------------------------------
// Fused middle: z_e = h2 @ Wez + bez ; VQ argmin (first-index tie-break);
// z_q = codebook[idx] ; z_st = z_e + (z_q - z_e) (replicate fp32 formula);
// d1 = relu(z_st @ Wd1 + bd1).
// One wave (64 lanes) per row. Reads h2 row and writes d1 row IN PLACE
// (same per-lane 16B address; register-held before store -> safe).
// ---------------------------------------------------------------------------
__global__ __launch_bounds__(256)
void vq_fused(const float* h2, const float* __restrict__ Wez,
              const float* __restrict__ bez, const float* __restrict__ cb,
              const float* __restrict__ Wd1, const float* __restrict__ bd1,
              float* __restrict__ ze_out, float* __restrict__ zq_out,
              float* d1) {
  const int lane = threadIdx.x & 63;
  const size_t row = ((size_t)blockIdx.x * 256 + threadIdx.x) >> 6;

  const float4 h = *reinterpret_cast<const float4*>(h2 + row * DIM2 + lane * 4);

  // partial z_e: this lane covers k = 4*lane .. 4*lane+3
  float p[DIMZ];
#pragma unroll
  for (int t = 0; t < DIMZ; t++) {
    const float* wz = Wez + (size_t)(lane * 4) * DIMZ + t;
    p[t] = fmaf(h.w, wz[3 * DIMZ],
           fmaf(h.z, wz[2 * DIMZ],
           fmaf(h.y, wz[1 * DIMZ], h.x * wz[0])));
  }
  // butterfly sum across the wave
#pragma unroll
  for (int s = 1; s < 64; s <<= 1)
#pragma unroll
    for (int t = 0; t < DIMZ; t++)
      p[t] += __shfl_xor(p[t], s, 64);

  // broadcast lane-0 copy so every lane uses identical z_e
  float ze[DIMZ];
#pragma unroll
  for (int t = 0; t < DIMZ; t++) ze[t] = __shfl(p[t], 0, 64) + bez[t];

  // dist for code v = lane (VOCAB == 64 == wave size)
  float s2 = 0.f, dot = 0.f;
  {
    const float* cv = cb + lane * DIMZ;
#pragma unroll
    for (int t = 0; t < DIMZ; t++) {
      s2  = fmaf(cv[t], cv[t], s2);
      dot = fmaf(ze[t], cv[t], dot);
    }
  }
  float dist = s2 - 2.f * dot;
  int idx = lane;
#pragma unroll
  for (int s = 1; s < 64; s <<= 1) {
    float od = __shfl_xor(dist, s, 64);
    int   oi = __shfl_xor(idx, s, 64);
    if (od < dist || (od == dist && oi < idx)) { dist = od; idx = oi; }
  }

  float zq[DIMZ], zst[DIMZ];
  const float* cq = cb + idx * DIMZ;
#pragma unroll
  for (int t = 0; t < DIMZ; t++) {
    zq[t]  = cq[t];
    zst[t] = ze[t] + (zq[t] - ze[t]);   // exact straight-through replication
  }

  // write z_e / z_q outputs (lane t writes element t)
#pragma unroll
  for (int t = 0; t < DIMZ; t++) {
    if (lane == t) {
      ze_out[row * DIMZ + t] = ze[t];
      zq_out[row * DIMZ + t] = zq[t];
    }
  }

  // d1 = relu(z_st @ Wd1 + bd1): lane computes cols 4*lane .. 4*lane+3
  const int n0 = lane * 4;
  float v0 = bd1[n0 + 0], v1 = bd1[n0 + 1], v2 = bd1[n0 + 2], v3 = bd1[n0 + 3];
#pragma unroll
  for (int t = 0; t < DIMZ; t++) {
    const float4 w = *reinterpret_cast<const float4*>(Wd1 + t * DIM2 + n0);
    v0 = fmaf(zst[t], w.x, v0);
    v1 = fmaf(zst[t], w.y, v1);
    v2 = fmaf(zst[t], w.z, v2);
    v3 = fmaf(zst[t], w.w, v3);
  }
  float4 o = make_float4(fmaxf(v0, 0.f), fmaxf(v1, 0.f),
                         fmaxf(v2, 0.f), fmaxf(v3, 0.f));
  *reinterpret_cast<float4*>(d1 + row * DIM2 + n0) = o;
}

// ---------------------------------------------------------------------------
extern "C" void kernel_launch(void* const* d_in, const int* in_sizes, int n_in,
                              void* d_out, int out_size, void* d_ws, size_t ws_size,
                              hipStream_t stream) {
  const float* x   = (const float*)d_in[0];
  const float* We1 = (const float*)d_in[1];
  const float* be1 = (const float*)d_in[2];
  const float* We2 = (const float*)d_in[3];
  const float* be2 = (const float*)d_in[4];
  const float* Wez = (const float*)d_in[5];
  const float* bez = (const float*)d_in[6];
  const float* Wd1 = (const float*)d_in[7];
  const float* bd1 = (const float*)d_in[8];
  const float* Wd2 = (const float*)d_in[9];
  const float* bd2 = (const float*)d_in[10];
  const float* Wd3 = (const float*)d_in[11];
  const float* bd3 = (const float*)d_in[12];
  const float* cb  = (const float*)d_in[13];

  float* out    = (float*)d_out;
  float* xp     = out;                                      // [B, 784]
  float* ze_out = out + (size_t)B_ROWS * DIM_IN;            // [B, 10]
  float* zq_out = ze_out + (size_t)B_ROWS * DIMZ;           // [B, 10]

  // workspace: bufA = h1 then d2 ([B,512] fp32), bufB = h2 then d1 ([B,256])
  float* bufA = (float*)d_ws;
  float* bufB = bufA + (size_t)B_ROWS * DIM1;               // total 192 MiB

  // E1: h1 = relu(x @ We1 + be1)         [B,784] -> [B,512]
  gemm_bias_act<1><<<dim3(DIM1 / BN, B_ROWS / BM), 256, 0, stream>>>(
      x, We1, be1, bufA, DIM1, DIM_IN);
  // E2: h2 = relu(h1 @ We2 + be2)        [B,512] -> [B,256]
  gemm_bias_act<1><<<dim3(DIM2 / BN, B_ROWS / BM), 256, 0, stream>>>(
      bufA, We2, be2, bufB, DIM2, DIM1);
  // z_e, VQ, z_q, d1 (in place over h2)
  vq_fused<<<B_ROWS / 4, 256, 0, stream>>>(
      bufB, Wez, bez, cb, Wd1, bd1, ze_out, zq_out, bufB);
  // D2: d2 = relu(d1 @ Wd2 + bd2)        [B,256] -> [B,512]
  gemm_bias_act<1><<<dim3(DIM1 / BN, B_ROWS / BM), 256, 0, stream>>>(
      bufB, Wd2, bd2, bufA, DIM1, DIM2);
  // D3: xp = sigmoid(d2 @ Wd3 + bd3)     [B,512] -> [B,784]
  gemm_bias_act<2><<<dim3((DIM_IN + BN - 1) / BN, B_ROWS / BM), 256, 0, stream>>>(
      bufA, Wd3, bd3, xp, DIM_IN, DIM1);
}

// Round 8
// 987.635 us; speedup vs baseline: 2.1711x; 2.1711x over previous
//
// Round 3 design (resubmit #5; rounds 2-7 were infra failures, never ran).
// MFMA fp16, linear-LDS m97-style GEMM (global_load_lds 16B staging,
// ds_read_b128 fragments). Encoder = 3-product hi/lo fp16 split (fp32-class
// z_e so VQ argmin matches reference); decoder = single fp16. Memory plan:
//   d_out: xh/xl planes in xp region (exact fit, dead before D3 writes xp);
//          we1/we2 planes + zero-buf in ze/zq region (dead before vq_fused).
//   d_ws (192 MiB): h1h | h1l | h2, overlaid later by d1h | d2h | wd2+wd3.
#include <hip/hip_runtime.h>
#include <cstdint>

#define B_ROWS 65536
#define DIM_IN 784
#define DIM1   512
#define DIM2   256
#define DIMZ   10

typedef _Float16 f16;
typedef f16 f16x4 __attribute__((ext_vector_type(4)));
typedef f16 f16x8 __attribute__((ext_vector_type(8)));
typedef float f32x4 __attribute__((ext_vector_type(4)));

#define AS1 __attribute__((address_space(1)))
#define AS3 __attribute__((address_space(3)))
#define GLD(src, dst) __builtin_amdgcn_global_load_lds((const AS1 void*)(src), (AS3 void*)(dst), 16, 0, 0)

// ---------------------------------------------------------------------------
// C[M,N] = act(A[M,K] @ W[K,N] + bias). A as AP fp16 planes [M][K] (linear),
// W as WP fp16 planes [N][K] (transposed, linear, rows padded to grid).
// EPI: 0 = relu -> split hi/lo f16 planes; 1 = relu -> f32; 2 = relu -> f16;
// 3 = sigmoid -> f32 (col<N guarded).
// 256 thr / 4 waves (2x2), 128x128 tile, BK=32, mfma_f32_16x16x32_f16.
// Both A and B fragments use the same (lane,j)->k map (k-permutation
// invariance) so linear LDS + one b128 per fragment is exact.
// ---------------------------------------------------------------------------
template<int AP, int WP, int EPI>
__global__ __launch_bounds__(256)
void gemm_mfma(const f16* __restrict__ Ah, const f16* __restrict__ Al,
               const f16* __restrict__ Wh, const f16* __restrict__ Wl,
               const float* __restrict__ bias,
               float* __restrict__ Cf, f16* __restrict__ Ch, f16* __restrict__ Cl,
               int N, int K, const f16* __restrict__ zb) {
  constexpr int NPL = AP + WP;
  __shared__ __align__(16) f16 lds[NPL * 4096];   // NPL planes of [128][32]

  const int tid  = threadIdx.x;
  const int wave = tid >> 6, lane = tid & 63;
  const int lr = lane & 15, lg = lane >> 4;
  const int wr = wave >> 1, wc = wave & 1;
  const int row0 = blockIdx.y * 128, col0 = blockIdx.x * 128;

  const f16* pl[NPL];
  int pb[NPL];
  pl[0] = Ah; pb[0] = row0;
  if constexpr (AP == 2) { pl[1] = Al; pb[1] = row0; }
  pl[AP] = Wh; pb[AP] = col0;
  if constexpr (WP == 2) { pl[AP + 1] = Wl; pb[AP + 1] = col0; }

  f32x4 acc[4][4] = {};

  const int KT = (K + 31) >> 5;
  for (int t = 0; t < KT; ++t) {
    const int kt = t << 5;
#pragma unroll
    for (int p = 0; p < NPL; ++p) {
#pragma unroll
      for (int i = 0; i < 2; ++i) {
        const int q = i * 256 + tid;          // 0..511: row r, 16B chunk c
        const int r = q >> 2, c = q & 3;
        const f16* s = pl[p] + (size_t)(pb[p] + r) * K + kt + c * 8;
        if (kt + c * 8 + 8 > K) s = zb + q * 8;     // zero tail (E1, kt=768)
        GLD(s, lds + p * 4096 + (i * 256 + wave * 64) * 8);
      }
    }
    __syncthreads();

    f16x8 af[AP][4], bf[WP][4];
#pragma unroll
    for (int mi = 0; mi < 4; ++mi)
#pragma unroll
      for (int p = 0; p < AP; ++p)
        af[p][mi] = *(const f16x8*)(lds + p * 4096 + (wr * 64 + mi * 16 + lr) * 32 + lg * 8);
#pragma unroll
    for (int ni = 0; ni < 4; ++ni)
#pragma unroll
      for (int p = 0; p < WP; ++p)
        bf[p][ni] = *(const f16x8*)(lds + (AP + p) * 4096 + (wc * 64 + ni * 16 + lr) * 32 + lg * 8);

#pragma unroll
    for (int mi = 0; mi < 4; ++mi)
#pragma unroll
      for (int ni = 0; ni < 4; ++ni)
        acc[mi][ni] = __builtin_amdgcn_mfma_f32_16x16x32_f16(af[0][mi], bf[0][ni], acc[mi][ni], 0, 0, 0);
    if constexpr (WP == 2) {
#pragma unroll
      for (int mi = 0; mi < 4; ++mi)
#pragma unroll
        for (int ni = 0; ni < 4; ++ni)
          acc[mi][ni] = __builtin_amdgcn_mfma_f32_16x16x32_f16(af[0][mi], bf[1][ni], acc[mi][ni], 0, 0, 0);
    }
    if constexpr (AP == 2) {
#pragma unroll
      for (int mi = 0; mi < 4; ++mi)
#pragma unroll
        for (int ni = 0; ni < 4; ++ni)
          acc[mi][ni] = __builtin_amdgcn_mfma_f32_16x16x32_f16(af[1][mi], bf[0][ni], acc[mi][ni], 0, 0, 0);
    }
    __syncthreads();
  }

  // epilogue: C/D map col = lane&15, row = (lane>>4)*4 + reg  [m89-verified]
#pragma unroll
  for (int mi = 0; mi < 4; ++mi) {
#pragma unroll
    for (int ni = 0; ni < 4; ++ni) {
      const int col = col0 + wc * 64 + ni * 16 + lr;
      const bool cok = (col < N);
      const float bv = cok ? bias[col] : 0.f;
#pragma unroll
      for (int r = 0; r < 4; ++r) {
        const int row = row0 + wr * 64 + mi * 16 + lg * 4 + r;
        float v = acc[mi][ni][r] + bv;
        if constexpr (EPI == 3) {
          v = 1.f / (1.f + __expf(-v));
          if (cok) Cf[(size_t)row * N + col] = v;
        } else {
          v = fmaxf(v, 0.f);
          if constexpr (EPI == 1) {
            Cf[(size_t)row * N + col] = v;
          } else {
            const size_t o = (size_t)row * N + col;
            const f16 h = (f16)v;
            Ch[o] = h;
            if constexpr (EPI == 0) Cl[o] = (f16)(v - (float)h);
          }
        }
      }
    }
  }
}

// ---------------------------------------------------------------------------
// prep kernels
// ---------------------------------------------------------------------------
__global__ __launch_bounds__(256)
void split_x(const float* __restrict__ x, f16* __restrict__ xh, f16* __restrict__ xl) {
  const unsigned i = blockIdx.x * 256u + threadIdx.x;   // < B*784
  const float v = x[i];
  const f16 h = (f16)v;
  xh[i] = h;
  xl[i] = (f16)(v - (float)h);
}

// out planes [gridDim.y][K] = W^T, zero-padded rows for n >= N
__global__ __launch_bounds__(256)
void split_w(const float* __restrict__ W, f16* __restrict__ oh, f16* __restrict__ ol,
             int N, int K) {
  const int k = blockIdx.x * 256 + threadIdx.x;
  const int n = blockIdx.y;
  if (k >= K) return;
  const float v = (n < N) ? W[(size_t)k * N + n] : 0.f;
  const f16 h = (f16)v;
  const size_t o = (size_t)n * K + k;
  oh[o] = h;
  if (ol) ol[o] = (f16)(v - (float)h);
}

__global__ __launch_bounds__(256)
void zero_f32(float* __restrict__ p, int n) {
  const int i = blockIdx.x * 256 + threadIdx.x;
  if (i < n) p[i] = 0.f;
}

// ---------------------------------------------------------------------------
// fused middle (round-1-validated math): z_e = h2@Wez+bez; VQ argmin
// (first-index tie-break); z_q; d1 = relu(z_st@Wd1+bd1) -> f16 plane.
// One wave per row; VOCAB == 64 == wave size.
// ---------------------------------------------------------------------------
__global__ __launch_bounds__(256)
void vq_fused(const float* __restrict__ h2, const float* __restrict__ Wez,
              const float* __restrict__ bez, const float* __restrict__ cb,
              const float* __restrict__ Wd1, const float* __restrict__ bd1,
              float* __restrict__ ze_out, float* __restrict__ zq_out,
              f16* __restrict__ d1h) {
  const int lane = threadIdx.x & 63;
  const size_t row = ((size_t)blockIdx.x * 256 + threadIdx.x) >> 6;

  const float4 h = *reinterpret_cast<const float4*>(h2 + row * DIM2 + lane * 4);

  float p[DIMZ];
#pragma unroll
  for (int t = 0; t < DIMZ; t++) {
    const float* wz = Wez + (size_t)(lane * 4) * DIMZ + t;
    p[t] = fmaf(h.w, wz[3 * DIMZ],
           fmaf(h.z, wz[2 * DIMZ],
           fmaf(h.y, wz[1 * DIMZ], h.x * wz[0])));
  }
#pragma unroll
  for (int s = 1; s < 64; s <<= 1)
#pragma unroll
    for (int t = 0; t < DIMZ; t++) p[t] += __shfl_xor(p[t], s, 64);

  float ze[DIMZ];
#pragma unroll
  for (int t = 0; t < DIMZ; t++) ze[t] = __shfl(p[t], 0, 64) + bez[t];

  float s2 = 0.f, dot = 0.f;
  {
    const float* cv = cb + lane * DIMZ;
#pragma unroll
    for (int t = 0; t < DIMZ; t++) {
      s2  = fmaf(cv[t], cv[t], s2);
      dot = fmaf(ze[t], cv[t], dot);
    }
  }
  float dist = s2 - 2.f * dot;
  int idx = lane;
#pragma unroll
  for (int s = 1; s < 64; s <<= 1) {
    const float od = __shfl_xor(dist, s, 64);
    const int   oi = __shfl_xor(idx, s, 64);
    if (od < dist || (od == dist && oi < idx)) { dist = od; idx = oi; }
  }

  float zq[DIMZ], zst[DIMZ];
  const float* cq = cb + idx * DIMZ;
#pragma unroll
  for (int t = 0; t < DIMZ; t++) {
    zq[t]  = cq[t];
    zst[t] = ze[t] + (zq[t] - ze[t]);
  }

#pragma unroll
  for (int t = 0; t < DIMZ; t++) {
    if (lane == t) {
      ze_out[row * DIMZ + t] = ze[t];
      zq_out[row * DIMZ + t] = zq[t];
    }
  }

  const int n0 = lane * 4;
  float v0 = bd1[n0 + 0], v1 = bd1[n0 + 1], v2 = bd1[n0 + 2], v3 = bd1[n0 + 3];
#pragma unroll
  for (int t = 0; t < DIMZ; t++) {
    const float4 w = *reinterpret_cast<const float4*>(Wd1 + t * DIM2 + n0);
    v0 = fmaf(zst[t], w.x, v0);
    v1 = fmaf(zst[t], w.y, v1);
    v2 = fmaf(zst[t], w.z, v2);
    v3 = fmaf(zst[t], w.w, v3);
  }
  f16x4 o;
  o[0] = (f16)fmaxf(v0, 0.f); o[1] = (f16)fmaxf(v1, 0.f);
  o[2] = (f16)fmaxf(v2, 0.f); o[3] = (f16)fmaxf(v3, 0.f);
  *(f16x4*)(d1h + row * DIM2 + n0) = o;
}

// ---------------------------------------------------------------------------
extern "C" void kernel_launch(void* const* d_in, const int* in_sizes, int n_in,
                              void* d_out, int out_size, void* d_ws, size_t ws_size,
                              hipStream_t stream) {
  const float* x   = (const float*)d_in[0];
  const float* We1 = (const float*)d_in[1];
  const float* be1 = (const float*)d_in[2];
  const float* We2 = (const float*)d_in[3];
  const float* be2 = (const float*)d_in[4];
  const float* Wez = (const float*)d_in[5];
  const float* bez = (const float*)d_in[6];
  const float* Wd1 = (const float*)d_in[7];
  const float* bd1 = (const float*)d_in[8];
  const float* Wd2 = (const float*)d_in[9];
  const float* bd2 = (const float*)d_in[10];
  const float* Wd3 = (const float*)d_in[11];
  const float* bd3 = (const float*)d_in[12];
  const float* cb  = (const float*)d_in[13];

  float* out    = (float*)d_out;
  float* xp     = out;                                   // [B,784]
  float* ze_out = out + (size_t)B_ROWS * DIM_IN;         // [B,10]
  float* zq_out = ze_out + (size_t)B_ROWS * DIMZ;        // [B,10]

  // ---- d_out overlays ----
  // xp region (205,520,896 B) = xh + xl planes, dead before D3 writes xp.
  f16* xh = (f16*)d_out;
  f16* xl = xh + (size_t)B_ROWS * DIM_IN;
  // ze/zq region (5,242,880 B): early weight planes + zero buf, all dead
  // before vq_fused writes ze/zq.
  char* wE = (char*)d_out + (size_t)B_ROWS * DIM_IN * 4;
  f16* we1h = (f16*)wE;                      // 802,816 B  ([512][784])
  f16* we1l = (f16*)(wE + 802816);           // 802,816 B
  f16* we2h = (f16*)(wE + 1605632);          // 262,144 B  ([256][512])
  f16* we2l = (f16*)(wE + 1867776);          // 262,144 B
  f16* zb   = (f16*)(wE + 2129920);          // 65,536 B zeros (tail staging)
  // total 2,195,456 B < 5,242,880 B

  // ---- d_ws overlays (needs exactly 192 MiB) ----
  char* w = (char*)d_ws;
  f16*   h1h = (f16*)w;                          // [  0, 64Mi)  [B][512]
  f16*   h1l = (f16*)(w + 67108864);             // [ 64,128Mi)
  float* h2  = (float*)(w + 134217728);          // [128,192Mi)  [B][256] f32
  f16*   d1h = (f16*)w;                          // over dead h1h (after E2)
  f16*   d2h = (f16*)(w + 33554432);             // over dead h1h/h1l (after VQ)
  f16*   wd2 = (f16*)(w + 134217728);            // over dead h2 ([512][256])
  f16*   wd3 = (f16*)(w + 134479872);            // over dead h2 ([896][512])

  zero_f32<<<64, 256, 0, stream>>>((float*)zb, 16384);
  split_x<<<(B_ROWS * DIM_IN) / 256, 256, 0, stream>>>(x, xh, xl);
  split_w<<<dim3(4, 512), 256, 0, stream>>>(We1, we1h, we1l, 512, 784);
  split_w<<<dim3(2, 256), 256, 0, stream>>>(We2, we2h, we2l, 256, 512);

  // E1: h1 = relu(x @ We1 + be1), split planes
  gemm_mfma<2, 2, 0><<<dim3(4, 512), 256, 0, stream>>>(
      xh, xl, we1h, we1l, be1, nullptr, h1h, h1l, DIM1, DIM_IN, zb);
  // E2: h2 = relu(h1 @ We2 + be2), f32
  gemm_mfma<2, 2, 1><<<dim3(2, 512), 256, 0, stream>>>(
      h1h, h1l, we2h, we2l, be2, h2, nullptr, nullptr, DIM2, DIM1, zb);
  // z_e / VQ / z_q / d1
  vq_fused<<<B_ROWS / 4, 256, 0, stream>>>(
      h2, Wez, bez, cb, Wd1, bd1, ze_out, zq_out, d1h);
  // late weight splits into dead h2 region
  split_w<<<dim3(1, 512), 256, 0, stream>>>(Wd2, wd2, nullptr, 512, 256);
  split_w<<<dim3(2, 896), 256, 0, stream>>>(Wd3, wd3, nullptr, 784, 512);
  // D2: d2 = relu(d1 @ Wd2 + bd2), f16
  gemm_mfma<1, 1, 2><<<dim3(4, 512), 256, 0, stream>>>(
      d1h, nullptr, wd2, nullptr, bd2, nullptr, d2h, nullptr, DIM1, DIM2, zb);
  // D3: xp = sigmoid(d2 @ Wd3 + bd3), f32
  gemm_mfma<1, 1, 3><<<dim3(7, 512), 256, 0, stream>>>(
      d2h, nullptr, wd3, nullptr, bd3, xp, nullptr, nullptr, DIM_IN, DIM1, zb);
}

// Round 9
// 797.331 us; speedup vs baseline: 2.6893x; 1.2387x over previous
//
// Round 9: round-3 verified design (987us, absmax 3.9e-3) + two changes:
//  (a) m204 bijective XCD-chunked blockIdx swizzle in all GEMMs (L2 reuse of
//      shared A-row-panels; E1 FETCH 461MB -> ~215MB predicted),
//  (b) split_x fused into E1 (ASRC=1): load x f32, split hi/lo in-register,
//      ds_write_b128 to the SAME linear LDS layout -> identical numerics,
//      eliminates the 410MB split_x pass.
// Encoder = 3-product hi/lo fp16 split (fp32-class z_e for VQ argmin safety);
// decoder = single fp16.
#include <hip/hip_runtime.h>
#include <cstdint>

#define B_ROWS 65536
#define DIM_IN 784
#define DIM1   512
#define DIM2   256
#define DIMZ   10

typedef _Float16 f16;
typedef f16 f16x4 __attribute__((ext_vector_type(4)));
typedef f16 f16x8 __attribute__((ext_vector_type(8)));
typedef float f32x4 __attribute__((ext_vector_type(4)));

#define AS1 __attribute__((address_space(1)))
#define AS3 __attribute__((address_space(3)))
#define GLD(src, dst) __builtin_amdgcn_global_load_lds((const AS1 void*)(src), (AS3 void*)(dst), 16, 0, 0)

// ---------------------------------------------------------------------------
// C[M,N] = act(A[M,K] @ W[K,N] + bias). W as WP fp16 planes [N][K] (transposed,
// linear, rows padded). A: ASRC=0 -> AP fp16 planes [M][K]; ASRC=1 -> f32
// source Ax, split to hi/lo planes in-register during staging (AP must be 2).
// EPI: 0 = relu -> split hi/lo f16; 1 = relu -> f32; 2 = relu -> f16;
// 3 = sigmoid -> f32 (col<N guarded).
// 256 thr / 4 waves (2x2), 128x128 tile, BK=32, mfma_f32_16x16x32_f16.
// ---------------------------------------------------------------------------
template<int AP, int WP, int EPI, int ASRC>
__global__ __launch_bounds__(256)
void gemm_mfma(const f16* __restrict__ Ah, const f16* __restrict__ Al,
               const f16* __restrict__ Wh, const f16* __restrict__ Wl,
               const float* __restrict__ bias,
               float* __restrict__ Cf, f16* __restrict__ Ch, f16* __restrict__ Cl,
               int N, int K, const f16* __restrict__ zb,
               const float* __restrict__ Ax) {
  constexpr int NPL = AP + WP;
  __shared__ __align__(16) f16 lds[NPL * 4096];   // NPL planes of [128][32]

  const int tid  = threadIdx.x;
  const int wave = tid >> 6, lane = tid & 63;
  const int lr = lane & 15, lg = lane >> 4;
  const int wr = wave >> 1, wc = wave & 1;

  // m204 bijective XCD-chunked swizzle: XCD i gets a contiguous logical chunk
  // (row-major), so col-blocks sharing an A-row-panel hit the same L2.
  const int gx  = gridDim.x;
  const int nwg = gx * gridDim.y;
  const int bid = blockIdx.y * gx + blockIdx.x;    // hw dispatch order (x-fastest)
  const int qq  = nwg >> 3, rm = nwg & 7;
  const int xcd = bid & 7, sub = bid >> 3;
  const int wg  = (xcd < rm ? xcd * (qq + 1) : rm * (qq + 1) + (xcd - rm) * qq) + sub;
  const int row0 = (wg / gx) * 128, col0 = (wg % gx) * 128;

  const f16* pl[NPL];
  int pb[NPL];
  if constexpr (ASRC == 0) {
    pl[0] = Ah; pb[0] = row0;
    if constexpr (AP == 2) { pl[1] = Al; pb[1] = row0; }
  }
  pl[AP] = Wh; pb[AP] = col0;
  if constexpr (WP == 2) { pl[AP + 1] = Wl; pb[AP + 1] = col0; }

  f32x4 acc[4][4] = {};

  constexpr int P0 = ASRC ? AP : 0;   // planes staged via global_load_lds
  const int KT = (K + 31) >> 5;
  for (int t = 0; t < KT; ++t) {
    const int kt = t << 5;

    if constexpr (ASRC == 1) {
      // A: f32 source -> hi/lo f16 planes (linear LDS layout identical to GLD)
#pragma unroll
      for (int i = 0; i < 2; ++i) {
        const int q = i * 256 + tid;        // 0..511
        const int r = q >> 2, c8 = q & 3;   // row, 8-f32 chunk
        const int k0 = kt + c8 * 8;
        f16x8 hi, lo;
        if (k0 + 8 <= K) {                  // K=784: chunk boundary is clean
          const float4 v0 = *(const float4*)(Ax + (size_t)(row0 + r) * K + k0);
          const float4 v1 = *(const float4*)(Ax + (size_t)(row0 + r) * K + k0 + 4);
          const float vv[8] = {v0.x, v0.y, v0.z, v0.w, v1.x, v1.y, v1.z, v1.w};
#pragma unroll
          for (int j = 0; j < 8; ++j) {
            const f16 h = (f16)vv[j];
            hi[j] = h; lo[j] = (f16)(vv[j] - (float)h);
          }
        } else {
#pragma unroll
          for (int j = 0; j < 8; ++j) { hi[j] = (f16)0.f; lo[j] = (f16)0.f; }
        }
        f16* dA = lds + (q << 3);
        *(f16x8*)(dA)        = hi;          // plane 0
        *(f16x8*)(dA + 4096) = lo;          // plane 1
      }
    }

#pragma unroll
    for (int p = P0; p < NPL; ++p) {
#pragma unroll
      for (int i = 0; i < 2; ++i) {
        const int q = i * 256 + tid;        // 0..511: row r, 16B chunk c
        const int r = q >> 2, c = q & 3;
        const f16* s = pl[p] + (size_t)(pb[p] + r) * K + kt + c * 8;
        if (kt + c * 8 + 8 > K) s = zb + q * 8;   // zero tail (E1 W, kt=768)
        GLD(s, lds + p * 4096 + (i * 256 + wave * 64) * 8);
      }
    }
    __syncthreads();

    f16x8 af[AP][4], bf[WP][4];
#pragma unroll
    for (int mi = 0; mi < 4; ++mi)
#pragma unroll
      for (int p = 0; p < AP; ++p)
        af[p][mi] = *(const f16x8*)(lds + p * 4096 + (wr * 64 + mi * 16 + lr) * 32 + lg * 8);
#pragma unroll
    for (int ni = 0; ni < 4; ++ni)
#pragma unroll
      for (int p = 0; p < WP; ++p)
        bf[p][ni] = *(const f16x8*)(lds + (AP + p) * 4096 + (wc * 64 + ni * 16 + lr) * 32 + lg * 8);

#pragma unroll
    for (int mi = 0; mi < 4; ++mi)
#pragma unroll
      for (int ni = 0; ni < 4; ++ni)
        acc[mi][ni] = __builtin_amdgcn_mfma_f32_16x16x32_f16(af[0][mi], bf[0][ni], acc[mi][ni], 0, 0, 0);
    if constexpr (WP == 2) {
#pragma unroll
      for (int mi = 0; mi < 4; ++mi)
#pragma unroll
        for (int ni = 0; ni < 4; ++ni)
          acc[mi][ni] = __builtin_amdgcn_mfma_f32_16x16x32_f16(af[0][mi], bf[1][ni], acc[mi][ni], 0, 0, 0);
    }
    if constexpr (AP == 2) {
#pragma unroll
      for (int mi = 0; mi < 4; ++mi)
#pragma unroll
        for (int ni = 0; ni < 4; ++ni)
          acc[mi][ni] = __builtin_amdgcn_mfma_f32_16x16x32_f16(af[1][mi], bf[0][ni], acc[mi][ni], 0, 0, 0);
    }
    __syncthreads();
  }

  // epilogue: C/D map col = lane&15, row = (lane>>4)*4 + reg  [m89-verified]
#pragma unroll
  for (int mi = 0; mi < 4; ++mi) {
#pragma unroll
    for (int ni = 0; ni < 4; ++ni) {
      const int col = col0 + wc * 64 + ni * 16 + lr;
      const bool cok = (col < N);
      const float bv = cok ? bias[col] : 0.f;
#pragma unroll
      for (int r = 0; r < 4; ++r) {
        const int row = row0 + wr * 64 + mi * 16 + lg * 4 + r;
        float v = acc[mi][ni][r] + bv;
        if constexpr (EPI == 3) {
          v = 1.f / (1.f + __expf(-v));
          if (cok) Cf[(size_t)row * N + col] = v;
        } else {
          v = fmaxf(v, 0.f);
          if constexpr (EPI == 1) {
            Cf[(size_t)row * N + col] = v;
          } else {
            const size_t o = (size_t)row * N + col;
            const f16 h = (f16)v;
            Ch[o] = h;
            if constexpr (EPI == 0) Cl[o] = (f16)(v - (float)h);
          }
        }
      }
    }
  }
}

// ---------------------------------------------------------------------------
// prep kernels
// ---------------------------------------------------------------------------
// out planes [gridDim.y][K] = W^T, zero-padded rows for n >= N
__global__ __launch_bounds__(256)
void split_w(const float* __restrict__ W, f16* __restrict__ oh, f16* __restrict__ ol,
             int N, int K) {
  const int k = blockIdx.x * 256 + threadIdx.x;
  const int n = blockIdx.y;
  if (k >= K) return;
  const float v = (n < N) ? W[(size_t)k * N + n] : 0.f;
  const f16 h = (f16)v;
  const size_t o = (size_t)n * K + k;
  oh[o] = h;
  if (ol) ol[o] = (f16)(v - (float)h);
}

__global__ __launch_bounds__(256)
void zero_f32(float* __restrict__ p, int n) {
  const int i = blockIdx.x * 256 + threadIdx.x;
  if (i < n) p[i] = 0.f;
}

// ---------------------------------------------------------------------------
// fused middle (validated r8): z_e = h2@Wez+bez; VQ argmin (first-index
// tie-break); z_q; d1 = relu(z_st@Wd1+bd1) -> f16 plane. One wave per row.
// ---------------------------------------------------------------------------
__global__ __launch_bounds__(256)
void vq_fused(const float* __restrict__ h2, const float* __restrict__ Wez,
              const float* __restrict__ bez, const float* __restrict__ cb,
              const float* __restrict__ Wd1, const float* __restrict__ bd1,
              float* __restrict__ ze_out, float* __restrict__ zq_out,
              f16* __restrict__ d1h) {
  const int lane = threadIdx.x & 63;
  const size_t row = ((size_t)blockIdx.x * 256 + threadIdx.x) >> 6;

  const float4 h = *reinterpret_cast<const float4*>(h2 + row * DIM2 + lane * 4);

  float p[DIMZ];
#pragma unroll
  for (int t = 0; t < DIMZ; t++) {
    const float* wz = Wez + (size_t)(lane * 4) * DIMZ + t;
    p[t] = fmaf(h.w, wz[3 * DIMZ],
           fmaf(h.z, wz[2 * DIMZ],
           fmaf(h.y, wz[1 * DIMZ], h.x * wz[0])));
  }
#pragma unroll
  for (int s = 1; s < 64; s <<= 1)
#pragma unroll
    for (int t = 0; t < DIMZ; t++) p[t] += __shfl_xor(p[t], s, 64);

  float ze[DIMZ];
#pragma unroll
  for (int t = 0; t < DIMZ; t++) ze[t] = __shfl(p[t], 0, 64) + bez[t];

  float s2 = 0.f, dot = 0.f;
  {
    const float* cv = cb + lane * DIMZ;
#pragma unroll
    for (int t = 0; t < DIMZ; t++) {
      s2  = fmaf(cv[t], cv[t], s2);
      dot = fmaf(ze[t], cv[t], dot);
    }
  }
  float dist = s2 - 2.f * dot;
  int idx = lane;
#pragma unroll
  for (int s = 1; s < 64; s <<= 1) {
    const float od = __shfl_xor(dist, s, 64);
    const int   oi = __shfl_xor(idx, s, 64);
    if (od < dist || (od == dist && oi < idx)) { dist = od; idx = oi; }
  }

  float zq[DIMZ], zst[DIMZ];
  const float* cq = cb + idx * DIMZ;
#pragma unroll
  for (int t = 0; t < DIMZ; t++) {
    zq[t]  = cq[t];
    zst[t] = ze[t] + (zq[t] - ze[t]);
  }

#pragma unroll
  for (int t = 0; t < DIMZ; t++) {
    if (lane == t) {
      ze_out[row * DIMZ + t] = ze[t];
      zq_out[row * DIMZ + t] = zq[t];
    }
  }

  const int n0 = lane * 4;
  float v0 = bd1[n0 + 0], v1 = bd1[n0 + 1], v2 = bd1[n0 + 2], v3 = bd1[n0 + 3];
#pragma unroll
  for (int t = 0; t < DIMZ; t++) {
    const float4 w = *reinterpret_cast<const float4*>(Wd1 + t * DIM2 + n0);
    v0 = fmaf(zst[t], w.x, v0);
    v1 = fmaf(zst[t], w.y, v1);
    v2 = fmaf(zst[t], w.z, v2);
    v3 = fmaf(zst[t], w.w, v3);
  }
  f16x4 o;
  o[0] = (f16)fmaxf(v0, 0.f); o[1] = (f16)fmaxf(v1, 0.f);
  o[2] = (f16)fmaxf(v2, 0.f); o[3] = (f16)fmaxf(v3, 0.f);
  *(f16x4*)(d1h + row * DIM2 + n0) = o;
}

// ---------------------------------------------------------------------------
extern "C" void kernel_launch(void* const* d_in, const int* in_sizes, int n_in,
                              void* d_out, int out_size, void* d_ws, size_t ws_size,
                              hipStream_t stream) {
  const float* x   = (const float*)d_in[0];
  const float* We1 = (const float*)d_in[1];
  const float* be1 = (const float*)d_in[2];
  const float* We2 = (const float*)d_in[3];
  const float* be2 = (const float*)d_in[4];
  const float* Wez = (const float*)d_in[5];
  const float* bez = (const float*)d_in[6];
  const float* Wd1 = (const float*)d_in[7];
  const float* bd1 = (const float*)d_in[8];
  const float* Wd2 = (const float*)d_in[9];
  const float* bd2 = (const float*)d_in[10];
  const float* Wd3 = (const float*)d_in[11];
  const float* bd3 = (const float*)d_in[12];
  const float* cb  = (const float*)d_in[13];

  float* out    = (float*)d_out;
  float* xp     = out;                                   // [B,784]
  float* ze_out = out + (size_t)B_ROWS * DIM_IN;         // [B,10]
  float* zq_out = ze_out + (size_t)B_ROWS * DIMZ;        // [B,10]

  // ---- d_out overlay: weight planes + zero-buf in ze/zq region (2.20 MB of
  // 5.24 MB), consumed by E1/E2 then fully overwritten by vq_fused.
  char* wE = (char*)d_out + (size_t)B_ROWS * DIM_IN * 4;
  f16* we1h = (f16*)wE;                      // 802,816 B  ([512][784])
  f16* we1l = (f16*)(wE + 802816);           // 802,816 B
  f16* we2h = (f16*)(wE + 1605632);          // 262,144 B  ([256][512])
  f16* we2l = (f16*)(wE + 1867776);          // 262,144 B
  f16* zb   = (f16*)(wE + 2129920);          // 65,536 B zeros (W-tail staging)

  // ---- d_ws overlays (192 MiB) ----
  char* w = (char*)d_ws;
  f16*   h1h = (f16*)w;                          // [  0, 64Mi)  [B][512]
  f16*   h1l = (f16*)(w + 67108864);             // [ 64,128Mi)
  float* h2  = (float*)(w + 134217728);          // [128,192Mi)  [B][256] f32
  f16*   d1h = (f16*)w;                          // over dead h1h (after E2)
  f16*   d2h = (f16*)(w + 33554432);             // over dead h1h/h1l (after VQ)
  f16*   wd2 = (f16*)(w + 134217728);            // over dead h2 ([512][256])
  f16*   wd3 = (f16*)(w + 134479872);            // over dead h2 ([896][512])

  zero_f32<<<64, 256, 0, stream>>>((float*)zb, 16384);
  split_w<<<dim3(4, 512), 256, 0, stream>>>(We1, we1h, we1l, 512, 784);
  split_w<<<dim3(2, 256), 256, 0, stream>>>(We2, we2h, we2l, 256, 512);

  // E1: h1 = relu(x @ We1 + be1) — x split in-register (ASRC=1)
  gemm_mfma<2, 2, 0, 1><<<dim3(4, 512), 256, 0, stream>>>(
      nullptr, nullptr, we1h, we1l, be1, nullptr, h1h, h1l, DIM1, DIM_IN, zb, x);
  // E2: h2 = relu(h1 @ We2 + be2), f32
  gemm_mfma<2, 2, 1, 0><<<dim3(2, 512), 256, 0, stream>>>(
      h1h, h1l, we2h, we2l, be2, h2, nullptr, nullptr, DIM2, DIM1, zb, nullptr);
  // z_e / VQ / z_q / d1
  vq_fused<<<B_ROWS / 4, 256, 0, stream>>>(
      h2, Wez, bez, cb, Wd1, bd1, ze_out, zq_out, d1h);
  // late weight splits into dead h2 region
  split_w<<<dim3(1, 512), 256, 0, stream>>>(Wd2, wd2, nullptr, 512, 256);
  split_w<<<dim3(2, 896), 256, 0, stream>>>(Wd3, wd3, nullptr, 784, 512);
  // D2: d2 = relu(d1 @ Wd2 + bd2), f16
  gemm_mfma<1, 1, 2, 0><<<dim3(4, 512), 256, 0, stream>>>(
      d1h, nullptr, wd2, nullptr, bd2, nullptr, d2h, nullptr, DIM1, DIM2, zb, nullptr);
  // D3: xp = sigmoid(d2 @ Wd3 + bd3), f32
  gemm_mfma<1, 1, 3, 0><<<dim3(7, 512), 256, 0, stream>>>(
      d2h, nullptr, wd3, nullptr, bd3, xp, nullptr, nullptr, DIM_IN, DIM1, zb, nullptr);
}